// Round 2
// baseline (1391.906 us; speedup 1.0000x reference)
//
#include <hip/hip_runtime.h>
#include <hip/hip_bf16.h>
#include <stdint.h>

// ---------------------------------------------------------------------------
// MessagePassingNodeModule: out = MLP([x | scatter_mean(edge_attr, dest) | u[batch]])
// Plan: CSR build (hist + scan + fill) -> gather-mean (bf16) -> fused bf16-MFMA MLP
// ---------------------------------------------------------------------------

typedef __attribute__((ext_vector_type(8))) __bf16 bf16x8;
typedef __attribute__((ext_vector_type(4))) float f32x4;

__device__ inline unsigned short f2bf(float f) {
    unsigned u = __float_as_uint(f);
    unsigned r = (u + 0x7fffu + ((u >> 16) & 1u)) >> 16;  // RNE
    return (unsigned short)r;
}

// ---- pack W1 [384][128] f32, W2 [128][128] f32 into MFMA B-fragment order (bf16)
__global__ void k_pack_w(const float* __restrict__ W1, const float* __restrict__ W2,
                         unsigned short* __restrict__ W1p, unsigned short* __restrict__ W2p) {
    int tid = blockIdx.x * blockDim.x + threadIdx.x;
    if (tid < 8 * 12 * 64) {
        int nt = tid / (12 * 64);
        int ks = (tid / 64) % 12;
        int l  = tid & 63;
        int k0 = ks * 32 + (l >> 4) * 8;
        int col = nt * 16 + (l & 15);
        #pragma unroll
        for (int i = 0; i < 8; ++i)
            W1p[tid * 8 + i] = f2bf(W1[(k0 + i) * 128 + col]);
    } else if (tid < 8 * 12 * 64 + 8 * 4 * 64) {
        int t2 = tid - 8 * 12 * 64;
        int nt = t2 / (4 * 64);
        int ks = (t2 / 64) % 4;
        int l  = t2 & 63;
        int k0 = ks * 32 + (l >> 4) * 8;
        int col = nt * 16 + (l & 15);
        #pragma unroll
        for (int i = 0; i < 8; ++i)
            W2p[t2 * 8 + i] = f2bf(W2[(k0 + i) * 128 + col]);
    }
}

// ---- histogram of destination nodes
__global__ void k_hist(const int* __restrict__ dest, int ne, int* __restrict__ counts) {
    int i = blockIdx.x * blockDim.x + threadIdx.x;
    int stride = gridDim.x * blockDim.x;
    for (; i < ne; i += stride) atomicAdd(&counts[dest[i]], 1);
}

// ---- scan stage 1: per-block sums of counts
__global__ void k_scan1(const int* __restrict__ counts, int n, int* __restrict__ bsum) {
    __shared__ int s[1024];
    int idx = blockIdx.x * 1024 + threadIdx.x;
    s[threadIdx.x] = (idx < n) ? counts[idx] : 0;
    __syncthreads();
    for (int off = 512; off > 0; off >>= 1) {
        if (threadIdx.x < off) s[threadIdx.x] += s[threadIdx.x + off];
        __syncthreads();
    }
    if (threadIdx.x == 0) bsum[blockIdx.x] = s[0];
}

// ---- scan stage 2: exclusive scan of block sums (nb <= 1024)
__global__ void k_scan2(const int* __restrict__ bsum, int nb, int* __restrict__ boff) {
    __shared__ int s[1024];
    int v = (threadIdx.x < nb) ? bsum[threadIdx.x] : 0;
    s[threadIdx.x] = v;
    __syncthreads();
    for (int off = 1; off < 1024; off <<= 1) {
        int t = (threadIdx.x >= off) ? s[threadIdx.x - off] : 0;
        __syncthreads();
        s[threadIdx.x] += t;
        __syncthreads();
    }
    if (threadIdx.x < nb) boff[threadIdx.x] = s[threadIdx.x] - v;
}

// ---- scan stage 3: final exclusive offsets; also init cursor
__global__ void k_scan3(const int* __restrict__ counts, int n, const int* __restrict__ boff,
                        int* __restrict__ offsets, int* __restrict__ cursor) {
    __shared__ int s[1024];
    int idx = blockIdx.x * 1024 + threadIdx.x;
    int v = (idx < n) ? counts[idx] : 0;
    s[threadIdx.x] = v;
    __syncthreads();
    for (int off = 1; off < 1024; off <<= 1) {
        int t = (threadIdx.x >= off) ? s[threadIdx.x - off] : 0;
        __syncthreads();
        s[threadIdx.x] += t;
        __syncthreads();
    }
    if (idx < n) {
        int e = s[threadIdx.x] - v + boff[blockIdx.x];
        offsets[idx] = e;
        cursor[idx] = e;
    }
}

// ---- fill CSR edge-id lists
__global__ void k_fill(const int* __restrict__ dest, int ne, int* __restrict__ cursor,
                       int* __restrict__ eids) {
    int i = blockIdx.x * blockDim.x + threadIdx.x;
    int stride = gridDim.x * blockDim.x;
    for (; i < ne; i += stride) {
        int d = dest[i];
        int p = atomicAdd(&cursor[d], 1);
        eids[p] = i;
    }
}

// ---- gather-mean: one wave per node, each lane owns 2 of 128 dims; output bf16 (packed u32)
__global__ void k_gather(const float* __restrict__ ea, const int* __restrict__ eids,
                         const int* __restrict__ offsets, const int* __restrict__ counts,
                         int n, unsigned int* __restrict__ agg) {
    int wid = blockIdx.x * 4 + (threadIdx.x >> 6);
    int lane = threadIdx.x & 63;
    if (wid >= n) return;
    int cnt = counts[wid];
    int start = offsets[wid];
    const float2* earow = (const float2*)ea;
    float ax = 0.f, ay = 0.f;
    int j = 0;
    for (; j + 2 <= cnt; j += 2) {  // 2 edge rows in flight
        int e0 = eids[start + j];
        int e1 = eids[start + j + 1];
        float2 v0 = earow[(long)e0 * 64 + lane];
        float2 v1 = earow[(long)e1 * 64 + lane];
        ax += v0.x + v1.x;
        ay += v0.y + v1.y;
    }
    if (j < cnt) {
        int e0 = eids[start + j];
        float2 v0 = earow[(long)e0 * 64 + lane];
        ax += v0.x;
        ay += v0.y;
    }
    float sc = (cnt > 0) ? 1.f / (float)cnt : 0.f;
    ax *= sc;
    ay *= sc;
    unsigned int pk = ((unsigned)f2bf(ay) << 16) | (unsigned)f2bf(ax);
    agg[(long)wid * 64 + lane] = pk;
}

// ---- fused MLP: feats=[x|agg|u[batch]] -> GEMM1(K=384) -> ReLU -> GEMM2(K=128) -> out
__global__ __launch_bounds__(256)
void k_mlp(const float* __restrict__ x, const unsigned int* __restrict__ agg,
           const float* __restrict__ u, const int* __restrict__ batch,
           const unsigned short* __restrict__ W1p, const float* __restrict__ b1,
           const unsigned short* __restrict__ W2p, const float* __restrict__ b2,
           float* __restrict__ out, int n) {
    // A tile: 64 rows x 384 k, bf16, row stride 392 (784B = 196 dw == 4 mod 32 -> 2-way only)
    __shared__ unsigned short A[64][392];  // 50176 B; H overlays A after GEMM1
    unsigned short (*H)[136] = (unsigned short(*)[136]) & A[0][0];  // 272B stride == 4 mod 32

    const int t = threadIdx.x;
    const int lane = t & 63;
    const int w = t >> 6;
    const int m0 = blockIdx.x * 64;

    // ---- stage A tile
    {
        int r = t >> 5;    // 0..7 (8 rows per pass)
        int c4 = t & 31;   // 0..31 (4-elem chunks)
        #pragma unroll
        for (int pass = 0; pass < 8; ++pass) {  // x section: k 0..127
            int row = pass * 8 + r;
            int m = m0 + row;
            float4 v = {0.f, 0.f, 0.f, 0.f};
            if (m < n) v = *(const float4*)&x[(long)m * 128 + c4 * 4];
            ushort4 pk;
            pk.x = f2bf(v.x); pk.y = f2bf(v.y); pk.z = f2bf(v.z); pk.w = f2bf(v.w);
            *(ushort4*)&A[row][c4 * 4] = pk;
        }
        #pragma unroll
        for (int pass = 0; pass < 8; ++pass) {  // agg section: k 128..255 (already bf16)
            int row = pass * 8 + r;
            int m = m0 + row;
            uint2 v = {0u, 0u};
            if (m < n) v = *(const uint2*)&agg[(long)m * 64 + c4 * 2];
            *(uint2*)&A[row][128 + c4 * 4] = v;
        }
        #pragma unroll
        for (int pass = 0; pass < 8; ++pass) {  // u section: k 256..383
            int row = pass * 8 + r;
            int m = m0 + row;
            float4 v = {0.f, 0.f, 0.f, 0.f};
            if (m < n) {
                int g = batch[m];
                v = *(const float4*)&u[g * 128 + c4 * 4];
            }
            ushort4 pk;
            pk.x = f2bf(v.x); pk.y = f2bf(v.y); pk.z = f2bf(v.z); pk.w = f2bf(v.w);
            *(ushort4*)&A[row][256 + c4 * 4] = pk;
        }
    }
    __syncthreads();

    // ---- GEMM1: h = relu(feats @ W1 + b1); wave w owns rows w*16..w*16+15
    f32x4 acc[8];
    #pragma unroll
    for (int i = 0; i < 8; ++i) acc[i] = (f32x4){0.f, 0.f, 0.f, 0.f};
    const int arow = w * 16 + (lane & 15);
    const int kg = (lane >> 4) * 8;
    #pragma unroll
    for (int ks = 0; ks < 12; ++ks) {
        bf16x8 a = *(const bf16x8*)&A[arow][ks * 32 + kg];
        #pragma unroll
        for (int nt = 0; nt < 8; ++nt) {
            bf16x8 b = *(const bf16x8*)&W1p[((nt * 12 + ks) * 64 + lane) * 8];
            acc[nt] = __builtin_amdgcn_mfma_f32_16x16x32_bf16(a, b, acc[nt], 0, 0, 0);
        }
    }
    __syncthreads();  // all A reads done; safe to overwrite with H

    // ---- epilogue 1: bias + relu -> H (bf16 in LDS)
    {
        int crow = w * 16 + (lane >> 4) * 4;
        int ccol = lane & 15;
        #pragma unroll
        for (int nt = 0; nt < 8; ++nt) {
            float bias = b1[nt * 16 + ccol];
            #pragma unroll
            for (int r2 = 0; r2 < 4; ++r2) {
                float hv = acc[nt][r2] + bias;
                hv = hv > 0.f ? hv : 0.f;
                H[crow + r2][nt * 16 + ccol] = f2bf(hv);
            }
        }
    }
    __syncthreads();

    // ---- GEMM2: out = h @ W2 + b2
    f32x4 acc2[8];
    #pragma unroll
    for (int i = 0; i < 8; ++i) acc2[i] = (f32x4){0.f, 0.f, 0.f, 0.f};
    #pragma unroll
    for (int ks = 0; ks < 4; ++ks) {
        bf16x8 a = *(const bf16x8*)&H[arow][ks * 32 + kg];
        #pragma unroll
        for (int nt = 0; nt < 8; ++nt) {
            bf16x8 b = *(const bf16x8*)&W2p[((nt * 4 + ks) * 64 + lane) * 8];
            acc2[nt] = __builtin_amdgcn_mfma_f32_16x16x32_bf16(a, b, acc2[nt], 0, 0, 0);
        }
    }

    // ---- epilogue 2: bias + store f32
    {
        int crow = w * 16 + (lane >> 4) * 4;
        int ccol = lane & 15;
        #pragma unroll
        for (int nt = 0; nt < 8; ++nt) {
            float bias = b2[nt * 16 + ccol];
            #pragma unroll
            for (int r2 = 0; r2 < 4; ++r2) {
                int m = m0 + crow + r2;
                if (m < n) out[(long)m * 128 + nt * 16 + ccol] = acc2[nt][r2] + bias;
            }
        }
    }
}

extern "C" void kernel_launch(void* const* d_in, const int* in_sizes, int n_in,
                              void* d_out, int out_size, void* d_ws, size_t ws_size,
                              hipStream_t stream) {
    const float* x    = (const float*)d_in[0];
    const float* ea   = (const float*)d_in[1];
    const float* u    = (const float*)d_in[2];
    const float* W1   = (const float*)d_in[3];
    const float* b1   = (const float*)d_in[4];
    const float* W2   = (const float*)d_in[5];
    const float* b2   = (const float*)d_in[6];
    const int* eidx   = (const int*)d_in[7];
    const int* batch  = (const int*)d_in[8];
    float* out = (float*)d_out;

    const int n_nodes = in_sizes[0] / 128;
    const int n_edges = in_sizes[1] / 128;
    const int* dest = eidx + n_edges;  // edge_index row 1

    // workspace carve (256B aligned)
    char* p = (char*)d_ws;
    auto carve = [&](size_t sz) {
        void* r = (void*)p;
        p += (sz + 255) & ~(size_t)255;
        return r;
    };
    int* counts  = (int*)carve((size_t)n_nodes * 4);
    int* offsets = (int*)carve((size_t)n_nodes * 4);
    int* cursor  = (int*)carve((size_t)n_nodes * 4);
    int* bsum    = (int*)carve(4096);
    int* boff    = (int*)carve(4096);
    int* eids    = (int*)carve((size_t)n_edges * 4);
    unsigned int* agg = (unsigned int*)carve((size_t)n_nodes * 64 * 4);
    unsigned short* W1p = (unsigned short*)carve((size_t)8 * 12 * 64 * 8 * 2);
    unsigned short* W2p = (unsigned short*)carve((size_t)8 * 4 * 64 * 8 * 2);

    hipMemsetAsync(counts, 0, (size_t)n_nodes * 4, stream);
    k_pack_w<<<32, 256, 0, stream>>>(W1, W2, W1p, W2p);
    k_hist<<<2048, 256, 0, stream>>>(dest, n_edges, counts);
    const int nb = (n_nodes + 1023) / 1024;
    k_scan1<<<nb, 1024, 0, stream>>>(counts, n_nodes, bsum);
    k_scan2<<<1, 1024, 0, stream>>>(bsum, nb, boff);
    k_scan3<<<nb, 1024, 0, stream>>>(counts, n_nodes, boff, offsets, cursor);
    k_fill<<<2048, 256, 0, stream>>>(dest, n_edges, cursor, eids);
    k_gather<<<(n_nodes + 3) / 4, 256, 0, stream>>>(ea, eids, offsets, counts, n_nodes, agg);
    k_mlp<<<(n_nodes + 63) / 64, 256, 0, stream>>>(x, agg, u, batch, W1p, b1, W2p, b2, out, n_nodes);
}